// Round 16
// baseline (925.580 us; speedup 1.0000x reference)
//
#include <hip/hip_runtime.h>
#include <hip/hip_bf16.h>

#define B_ 4
#define T_ 2048
#define C_ 2048
#define D_ 2048
#define F_ 8192
#define BT_ (B_*T_)
#define NCH 64
#define LCH 32

using bf16 = __hip_bfloat16;
typedef __attribute__((ext_vector_type(8))) short bf16x8;
typedef __attribute__((ext_vector_type(4))) float f32x4;

template<bool V> struct BC { static constexpr bool value = V; };

struct bf4 { bf16 a, b, c, d; };

__device__ __forceinline__ bf4 to_bf4(float x, float y, float z, float w) {
  bf4 r;
  r.a = __float2bfloat16(x); r.b = __float2bfloat16(y);
  r.c = __float2bfloat16(z); r.d = __float2bfloat16(w);
  return r;
}

__device__ __forceinline__ void cvt_body(const float* __restrict__ in,
                                         bf16* __restrict__ out,
                                         int i, int stride, int n4) {
  for (; i < n4; i += stride) {
    float4 v = ((const float4*)in)[i];
    ((bf4*)out)[i] = to_bf4(v.x, v.y, v.z, v.w);
  }
}

// ---------------- block-wide reduce of 4 values (256 threads) ----------------
__device__ __forceinline__ void block_reduce4(float v[4], float out[4]) {
  #pragma unroll
  for (int i = 0; i < 4; ++i)
    #pragma unroll
    for (int off = 1; off < 64; off <<= 1)
      v[i] += __shfl_xor(v[i], off);
  __shared__ float red[4][4];
  int wave = threadIdx.x >> 6, lane = threadIdx.x & 63;
  if (lane == 0) {
    red[wave][0] = v[0]; red[wave][1] = v[1];
    red[wave][2] = v[2]; red[wave][3] = v[3];
  }
  __syncthreads();
  #pragma unroll
  for (int i = 0; i < 4; ++i)
    out[i] = red[0][i] + red[1][i] + red[2][i] + red[3][i];
}

// ========== merged: LN+mix (TimeMix) for blocks [0,BT_), cvt4 for the rest ==========
__global__ __launch_bounds__(256) void mixcvt1_kernel(
    const float* __restrict__ x, const float* __restrict__ w, const float* __restrict__ b,
    const float* __restrict__ tmk, const float* __restrict__ tmv, const float* __restrict__ tmr,
    bf16* __restrict__ xk, bf16* __restrict__ xv, bf16* __restrict__ xr,
    const float* __restrict__ W0, const float* __restrict__ W1,
    const float* __restrict__ W2, const float* __restrict__ W3,
    bf16* __restrict__ o0, bf16* __restrict__ o1,
    bf16* __restrict__ o2, bf16* __restrict__ o3) {
  if (blockIdx.x >= BT_) {
    const int lb4 = blockIdx.x - BT_;
    const int sub = lb4 >> 10;
    const int lb = lb4 & 1023;
    const float* in = (sub == 0) ? W0 : (sub == 1) ? W1 : (sub == 2) ? W2 : W3;
    bf16* o = (sub == 0) ? o0 : (sub == 1) ? o1 : (sub == 2) ? o2 : o3;
    cvt_body(in, o, lb * 256 + threadIdx.x, 1024 * 256, D_ * C_ / 4);
    return;
  }
  const int row = blockIdx.x;
  const int t = row & (T_ - 1);
  const bool hasPrev = (t != 0);
  const int tid = threadIdx.x;
  const float* xc = x + (size_t)row * C_;
  const float* xp = xc - C_;
  float c[8], p[8];
  *(float4*)&c[0] = *(const float4*)(xc + tid * 4);
  *(float4*)&c[4] = *(const float4*)(xc + tid * 4 + 1024);
  if (hasPrev) {
    *(float4*)&p[0] = *(const float4*)(xp + tid * 4);
    *(float4*)&p[4] = *(const float4*)(xp + tid * 4 + 1024);
  } else {
    #pragma unroll
    for (int j = 0; j < 8; ++j) p[j] = 0.f;
  }
  float v[4] = {0.f, 0.f, 0.f, 0.f}, tot[4];
  #pragma unroll
  for (int j = 0; j < 8; ++j) {
    v[0] += c[j]; v[1] += c[j] * c[j];
    v[2] += p[j]; v[3] += p[j] * p[j];
  }
  block_reduce4(v, tot);
  const float muc = tot[0] * (1.f / C_);
  const float rsc = rsqrtf(tot[1] * (1.f / C_) - muc * muc + 1e-5f);
  const float mup = tot[2] * (1.f / C_);
  const float rsp = rsqrtf(tot[3] * (1.f / C_) - mup * mup + 1e-5f);
  float wv[8], bv[8], mk[8], mv[8], mr[8];
  #pragma unroll
  for (int half = 0; half < 2; ++half) {
    int i = tid * 4 + half * 1024;
    *(float4*)&wv[half*4] = *(const float4*)(w + i);
    *(float4*)&bv[half*4] = *(const float4*)(b + i);
    *(float4*)&mk[half*4] = *(const float4*)(tmk + i);
    *(float4*)&mv[half*4] = *(const float4*)(tmv + i);
    *(float4*)&mr[half*4] = *(const float4*)(tmr + i);
  }
  float ok[8], ov[8], orr[8];
  #pragma unroll
  for (int j = 0; j < 8; ++j) {
    float h  = (c[j] - muc) * rsc * wv[j] + bv[j];
    float hh = hasPrev ? ((p[j] - mup) * rsp * wv[j] + bv[j]) : 0.f;
    ok[j]  = hh + mk[j] * (h - hh);
    ov[j]  = hh + mv[j] * (h - hh);
    orr[j] = hh + mr[j] * (h - hh);
  }
  size_t ro = (size_t)row * C_;
  #pragma unroll
  for (int half = 0; half < 2; ++half) {
    int i = tid * 4 + half * 1024;
    *(bf4*)(xk + ro + i) = to_bf4(ok[half*4], ok[half*4+1], ok[half*4+2], ok[half*4+3]);
    *(bf4*)(xv + ro + i) = to_bf4(ov[half*4], ov[half*4+1], ov[half*4+2], ov[half*4+3]);
    *(bf4*)(xr + ro + i) = to_bf4(orr[half*4], orr[half*4+1], orr[half*4+2], orr[half*4+3]);
  }
}

// ========== merged: LN+mix (ChannelMix) for [0,BT_), Wck cvt after ==========
__global__ __launch_bounds__(256) void mixcvt2_kernel(
    const float* __restrict__ x, const float* __restrict__ w, const float* __restrict__ b,
    const float* __restrict__ cmk, const float* __restrict__ cmr,
    bf16* __restrict__ xk2, bf16* __restrict__ xr2,
    const float* __restrict__ Wck, bf16* __restrict__ Wck_b) {
  if (blockIdx.x >= BT_) {
    const int lb = blockIdx.x - BT_;
    cvt_body(Wck, Wck_b, lb * 256 + threadIdx.x, 2048 * 256, F_ * C_ / 4);
    return;
  }
  const int row = blockIdx.x;
  const int t = row & (T_ - 1);
  const bool hasPrev = (t != 0);
  const int tid = threadIdx.x;
  const float* xc = x + (size_t)row * C_;
  const float* xp = xc - C_;
  float c[8], p[8];
  *(float4*)&c[0] = *(const float4*)(xc + tid * 4);
  *(float4*)&c[4] = *(const float4*)(xc + tid * 4 + 1024);
  if (hasPrev) {
    *(float4*)&p[0] = *(const float4*)(xp + tid * 4);
    *(float4*)&p[4] = *(const float4*)(xp + tid * 4 + 1024);
  } else {
    #pragma unroll
    for (int j = 0; j < 8; ++j) p[j] = 0.f;
  }
  float v[4] = {0.f, 0.f, 0.f, 0.f}, tot[4];
  #pragma unroll
  for (int j = 0; j < 8; ++j) {
    v[0] += c[j]; v[1] += c[j] * c[j];
    v[2] += p[j]; v[3] += p[j] * p[j];
  }
  block_reduce4(v, tot);
  const float muc = tot[0] * (1.f / C_);
  const float rsc = rsqrtf(tot[1] * (1.f / C_) - muc * muc + 1e-5f);
  const float mup = tot[2] * (1.f / C_);
  const float rsp = rsqrtf(tot[3] * (1.f / C_) - mup * mup + 1e-5f);
  float wv[8], bv[8], mk[8], mr[8];
  #pragma unroll
  for (int half = 0; half < 2; ++half) {
    int i = tid * 4 + half * 1024;
    *(float4*)&wv[half*4] = *(const float4*)(w + i);
    *(float4*)&bv[half*4] = *(const float4*)(b + i);
    *(float4*)&mk[half*4] = *(const float4*)(cmk + i);
    *(float4*)&mr[half*4] = *(const float4*)(cmr + i);
  }
  float ok[8], orr[8];
  #pragma unroll
  for (int j = 0; j < 8; ++j) {
    float h  = (c[j] - muc) * rsc * wv[j] + bv[j];
    float hh = hasPrev ? ((p[j] - mup) * rsp * wv[j] + bv[j]) : 0.f;
    ok[j]  = hh + mk[j] * (h - hh);
    orr[j] = hh + mr[j] * (h - hh);
  }
  size_t ro = (size_t)row * C_;
  #pragma unroll
  for (int half = 0; half < 2; ++half) {
    int i = tid * 4 + half * 1024;
    *(bf4*)(xk2 + ro + i) = to_bf4(ok[half*4], ok[half*4+1], ok[half*4+2], ok[half*4+3]);
    *(bf4*)(xr2 + ro + i) = to_bf4(orr[half*4], orr[half*4+1], orr[half*4+2], orr[half*4+3]);
  }
}

// ================= chunk-parallel WKV =================
__global__ __launch_bounds__(256) void wkv_pass1(
    const bf16* __restrict__ kp, const bf16* __restrict__ vp,
    const float* __restrict__ td,
    float* __restrict__ sA, float* __restrict__ sB, float* __restrict__ sP) {
  const int g = blockIdx.x * 256 + threadIdx.x;   // b(2) | c(6) | d(11)
  const int d = g & (D_ - 1);
  const int c = (g >> 11) & (NCH - 1);
  const int b = g >> 17;
  const float w = -__expf(td[d]);
  const size_t base = ((size_t)b * T_ + c * LCH) * D_ + d;
  float aa = 0.f, bb = 0.f, pp = -1e38f;
  #pragma unroll 4
  for (int j = 0; j < LCH; ++j) {
    float kt = __bfloat162float(kp[base + (size_t)j * D_]);
    float vt = __bfloat162float(vp[base + (size_t)j * D_]);
    float ww2 = pp + w;
    float p2 = fmaxf(ww2, kt);
    float e1 = __expf(ww2 - p2), e2 = __expf(kt - p2);
    aa = e1 * aa + e2 * vt;
    bb = e1 * bb + e2;
    pp = p2;
  }
  const int sidx = ((b * NCH + c) << 11) + d;
  sA[sidx] = aa; sB[sidx] = bb; sP[sidx] = pp;
}

// serial exclusive prefix over chunks: thread = (b,d), coalesced across d
__global__ __launch_bounds__(256) void wkv_pass2(
    const float* __restrict__ td,
    float* __restrict__ sA, float* __restrict__ sB, float* __restrict__ sP) {
  const int g = blockIdx.x * 256 + threadIdx.x;   // b(2) | d(11)
  const int d = g & (D_ - 1);
  const int b = g >> 11;
  const float wL = -__expf(td[d]) * (float)LCH;
  float aa = 0.f, bb = 0.f, pp = -1e38f;
  for (int c = 0; c < NCH; ++c) {
    const int sidx = ((b * NCH + c) << 11) + d;
    float la = sA[sidx], lb = sB[sidx], lp = sP[sidx];
    sA[sidx] = aa; sB[sidx] = bb; sP[sidx] = pp;   // exclusive prefix
    float ww2 = pp + wL;
    float q = fmaxf(ww2, lp);
    float e1 = __expf(ww2 - q), e2 = __expf(lp - q);
    aa = e1 * aa + e2 * la;
    bb = e1 * bb + e2 * lb;
    pp = q;
  }
}

__global__ __launch_bounds__(256) void wkv_pass3(
    const bf16* __restrict__ kp, const bf16* __restrict__ vp, const bf16* __restrict__ rp,
    const float* __restrict__ td, const float* __restrict__ tfp,
    const float* __restrict__ sA, const float* __restrict__ sB, const float* __restrict__ sP,
    bf16* __restrict__ rwkv) {
  const int g = blockIdx.x * 256 + threadIdx.x;
  const int d = g & (D_ - 1);
  const int c = (g >> 11) & (NCH - 1);
  const int b = g >> 17;
  const float w = -__expf(td[d]);
  const float u = tfp[d];
  const int sidx = ((b * NCH + c) << 11) + d;
  float aa = sA[sidx], bb = sB[sidx], pp = sP[sidx];
  const size_t base = ((size_t)b * T_ + c * LCH) * D_ + d;
  #pragma unroll 4
  for (int j = 0; j < LCH; ++j) {
    float kt = __bfloat162float(kp[base + (size_t)j * D_]);
    float vt = __bfloat162float(vp[base + (size_t)j * D_]);
    float rt = __bfloat162float(rp[base + (size_t)j * D_]);
    float ww = u + kt;
    float p = fmaxf(pp, ww);
    float e1 = __expf(pp - p);
    float e2 = __expf(ww - p);
    float outv = (e1 * aa + e2 * vt) / (e1 * bb + e2);
    float sr = 1.f / (1.f + __expf(-rt));
    rwkv[base + (size_t)j * D_] = __float2bfloat16(sr * outv);
    float ww2 = pp + w;
    float p2 = fmaxf(ww2, kt);
    float e1b = __expf(ww2 - p2);
    float e2b = __expf(kt - p2);
    aa = e1b * aa + e2b * vt;
    bb = e1b * bb + e2b;
    pp = p2;
  }
}

// ================= 256x256 8-phase bf16 MFMA GEMM core (r11 body) =================
template<int EPI>
__device__ __forceinline__ void gemm_core(
    const bf16* __restrict__ A, const bf16* __restrict__ Bt,
    int N, int K, int id, int nwg,
    float* __restrict__ outF, bf16* __restrict__ outB,
    const float* __restrict__ addP, const bf16* __restrict__ sigP,
    char* lds) {
  const int tid = threadIdx.x;
  const int wid = tid >> 6, lane = tid & 63;
  const int wm = wid >> 2, wn = wid & 3;

  const int cpx = nwg >> 3;
  const int sid = (id & 7) * cpx + (id >> 3);
  const int nx = N >> 8;
  const int band = sid / (4 * nx);
  const int rem = sid - band * (4 * nx);
  const int bx = rem >> 2;
  const int by = band * 4 + (rem & 3);
  const int tileM = by * 256, tileN = bx * 256;

  const int NT = K >> 6;

  const int srow_lo = wid * 8 + (lane >> 3);
  const int scel = ((lane & 7) ^ (lane >> 3)) << 3;

  const bf16* pA[2][2];
  const bf16* pB[2][2];
  #pragma unroll
  for (int h = 0; h < 2; ++h)
    #pragma unroll
    for (int j = 0; j < 2; ++j) {
      pA[h][j] = A  + (size_t)(tileM + h * 128 + srow_lo + j * 64) * K + scel;
      pB[h][j] = Bt + (size_t)(tileN + h * 128 + srow_lo + j * 64) * K + scel;
    }
  const int ldsW = wid * 1024;

  auto stA = [&](int par, int h, int eo) {
    #pragma unroll
    for (int j = 0; j < 2; ++j)
      __builtin_amdgcn_global_load_lds(
          (const __attribute__((address_space(1))) void*)(pA[h][j] + eo),
          (__attribute__((address_space(3))) void*)(lds + par * 32768 + h * 16384 + j * 8192 + ldsW),
          16, 0, 0);
  };
  auto stB = [&](int par, int h, int eo) {
    #pragma unroll
    for (int j = 0; j < 2; ++j)
      __builtin_amdgcn_global_load_lds(
          (const __attribute__((address_space(1))) void*)(pB[h][j] + eo),
          (__attribute__((address_space(3))) void*)(lds + 65536 + par * 32768 + h * 16384 + j * 8192 + ldsW),
          16, 0, 0);
  };

  const int lane15 = lane & 15;
  const int kswz0 = ((lane >> 4) * 16) ^ ((lane & 7) << 4);
  const int aBase = (wm * 128 + lane15) * 128;
  const int bBase = (wn * 64 + lane15) * 128;

  f32x4 acc[8][4] = {};

  stB(0, 0, 0); stB(0, 1, 0); stA(0, 0, 0); stA(0, 1, 0); stB(1, 0, 64); stB(1, 1, 64);
  asm volatile("s_waitcnt vmcnt(4)" : : : "memory");
  __builtin_amdgcn_s_barrier();
  __builtin_amdgcn_sched_barrier(0);

  auto tileBody = [&](int par, auto doa, auto dob, int aEo, int bEo) {
    constexpr bool DOA = decltype(doa)::value;
    constexpr bool DOB = decltype(dob)::value;
    const char* Ab = lds + (par << 15);
    const char* Bb = lds + 65536 + (par << 15);
    bf16x8 bfr[4][2];
    #pragma unroll
    for (int q = 0; q < 4; ++q) {
      if (q == 0) {
        #pragma unroll
        for (int n = 0; n < 4; ++n) {
          bfr[n][0] = *(const bf16x8*)(Bb + bBase + n * 2048 + kswz0);
          bfr[n][1] = *(const bf16x8*)(Bb + bBase + n * 2048 + (kswz0 ^ 64));
        }
      }
      bf16x8 am[2][2];
      #pragma unroll
      for (int mm = 0; mm < 2; ++mm) {
        am[mm][0] = *(const bf16x8*)(Ab + aBase + q * 4096 + mm * 2048 + kswz0);
        am[mm][1] = *(const bf16x8*)(Ab + aBase + q * 4096 + mm * 2048 + (kswz0 ^ 64));
      }
      if constexpr (DOA) {
        if (q == 0) stA(par ^ 1, 0, aEo);
        if (q == 1) stA(par ^ 1, 1, aEo);
      }
      if constexpr (DOB) {
        if (q == 2) stB(par, 0, bEo);
        if (q == 3) stB(par, 1, bEo);
      }
      if (q == 0)
        asm volatile("s_waitcnt lgkmcnt(8)" : : : "memory");
      __builtin_amdgcn_sched_barrier(0);
      __builtin_amdgcn_s_barrier();
      __builtin_amdgcn_sched_barrier(0);
      __builtin_amdgcn_s_setprio(1);
      #pragma unroll
      for (int kk = 0; kk < 2; ++kk)
        #pragma unroll
        for (int n = 0; n < 4; ++n) {
          acc[2*q+0][n] = __builtin_amdgcn_mfma_f32_16x16x32_bf16(am[0][kk], bfr[n][kk], acc[2*q+0][n], 0, 0, 0);
          acc[2*q+1][n] = __builtin_amdgcn_mfma_f32_16x16x32_bf16(am[1][kk], bfr[n][kk], acc[2*q+1][n], 0, 0, 0);
        }
      __builtin_amdgcn_s_setprio(0);
      __builtin_amdgcn_sched_barrier(0);
      if (q == 3) {
        if constexpr (DOB)      asm volatile("s_waitcnt vmcnt(4)" : : : "memory");
        else if constexpr (DOA) asm volatile("s_waitcnt vmcnt(0)" : : : "memory");
      }
      __builtin_amdgcn_s_barrier();
      __builtin_amdgcn_sched_barrier(0);
    }
  };

  for (int t = 0; t < NT - 2; t += 2) {
    tileBody(0, BC<true>{}, BC<true>{}, 64, 128);
    tileBody(1, BC<true>{}, BC<true>{}, 128, 192);
    #pragma unroll
    for (int h = 0; h < 2; ++h)
      #pragma unroll
      for (int j = 0; j < 2; ++j) { pA[h][j] += 128; pB[h][j] += 128; }
  }
  tileBody(0, BC<true>{}, BC<false>{}, 64, 0);
  tileBody(1, BC<false>{}, BC<false>{}, 0, 0);

  const int erow0 = tileM + wm * 128 + (lane >> 4) * 4;
  const int ecol0 = tileN + wn * 64 + lane15;
  #pragma unroll
  for (int m = 0; m < 8; ++m) {
    #pragma unroll
    for (int n = 0; n < 4; ++n) {
      #pragma unroll
      for (int r = 0; r < 4; ++r) {
        const int grow = erow0 + m * 16 + r;
        const int gcol = ecol0 + n * 16;
        const size_t idx = (size_t)grow * N + gcol;
        const float val = acc[m][n][r];
        if constexpr (EPI == 0) {
          outB[idx] = __float2bfloat16(val);
        } else if constexpr (EPI == 1) {
          float tt = fmaxf(val, 0.f);
          outB[idx] = __float2bfloat16(tt * tt);
        } else if constexpr (EPI == 2) {
          outF[idx] = addP[idx] + val;
        } else if constexpr (EPI == 3) {
          outB[idx] = __float2bfloat16(1.f / (1.f + __expf(-val)));
        } else {
          outF[idx] = addP[idx] + __bfloat162float(sigP[idx]) * val;
        }
      }
    }
  }
}

template<int EPI>
__global__ __launch_bounds__(512, 2) void gemm256(
    const bf16* __restrict__ A, const bf16* __restrict__ Bt,
    int N, int K,
    float* __restrict__ outF, bf16* __restrict__ outB,
    const float* __restrict__ addP, const bf16* __restrict__ sigP) {
  __shared__ alignas(16) char lds[131072];
  gemm_core<EPI>(A, Bt, N, K, blockIdx.x, gridDim.x, outF, outB, addP, sigP, lds);
}

// merged k/v/r GEMM (blocks 0..767) + trailing Wcr cvt (768..1279)
__global__ __launch_bounds__(512, 2) void gemm_kvr_cvt(
    const bf16* __restrict__ A0, const bf16* __restrict__ A1, const bf16* __restrict__ A2,
    const bf16* __restrict__ B0, const bf16* __restrict__ B1, const bf16* __restrict__ B2,
    bf16* __restrict__ O0, bf16* __restrict__ O1, bf16* __restrict__ O2,
    const float* __restrict__ Wcr, bf16* __restrict__ Wcr_b) {
  __shared__ alignas(16) char lds[131072];
  if (blockIdx.x >= 768) {
    cvt_body(Wcr, Wcr_b, (blockIdx.x - 768) * 512 + threadIdx.x, 512 * 512, C_ * C_ / 4);
    return;
  }
  const int sub = blockIdx.x >> 8;        // 0..2
  const int bid = blockIdx.x & 255;
  const bf16* A  = (sub == 0) ? A0 : (sub == 1) ? A1 : A2;
  const bf16* Bt = (sub == 0) ? B0 : (sub == 1) ? B1 : B2;
  bf16* O        = (sub == 0) ? O0 : (sub == 1) ? O1 : O2;
  gemm_core<0>(A, Bt, D_, C_, bid, 256, nullptr, O, nullptr, nullptr, lds);
}

// merged: kf-GEMM (blocks 0..1023) + trailing Wcv cvt (1024..1535)
__global__ __launch_bounds__(512, 2) void gemm_kf_cvt(
    const bf16* __restrict__ A, const bf16* __restrict__ Bt, bf16* __restrict__ kf,
    const float* __restrict__ Wcv, bf16* __restrict__ Wcv_b) {
  __shared__ alignas(16) char lds[131072];
  if (blockIdx.x >= 1024) {
    cvt_body(Wcv, Wcv_b, (blockIdx.x - 1024) * 512 + threadIdx.x, 512 * 512, C_ * F_ / 4);
    return;
  }
  gemm_core<1>(A, Bt, F_, C_, blockIdx.x, 1024, nullptr, kf, nullptr, nullptr, lds);
}

// ---------------- launch ----------------
extern "C" void kernel_launch(void* const* d_in, const int* in_sizes, int n_in,
                              void* d_out, int out_size, void* d_ws, size_t ws_size,
                              hipStream_t stream) {
  const float* x    = (const float*)d_in[0];
  const float* ln1w = (const float*)d_in[1];
  const float* ln1b = (const float*)d_in[2];
  const float* ln2w = (const float*)d_in[3];
  const float* ln2b = (const float*)d_in[4];
  const float* tmk  = (const float*)d_in[5];
  const float* tmv  = (const float*)d_in[6];
  const float* tmr  = (const float*)d_in[7];
  const float* td   = (const float*)d_in[8];
  const float* tf   = (const float*)d_in[9];
  const float* Wk   = (const float*)d_in[10];
  const float* Wv   = (const float*)d_in[11];
  const float* Wr   = (const float*)d_in[12];
  const float* Wo   = (const float*)d_in[13];
  const float* cmk  = (const float*)d_in[14];
  const float* cmr  = (const float*)d_in[15];
  const float* Wck  = (const float*)d_in[16];
  const float* Wcv  = (const float*)d_in[17];
  const float* Wcr  = (const float*)d_in[18];
  float* out = (float*)d_out;

  char* ws = (char*)d_ws;
  const size_t MB = 1ull << 20;
  bf16* R0 = (bf16*)(ws + 0 * MB);     // TimeMix weights -> wkv state -> Wck_b
  bf16* R1 = (bf16*)(ws + 32 * MB);
  bf16* R2 = (bf16*)(ws + 64 * MB);
  bf16* R3 = (bf16*)(ws + 96 * MB);
  bf16* R4 = (bf16*)(ws + 128 * MB);   // [128,256): k_|v_|r_ then kf

  // TimeMix activations
  bf16* xk = R1, *xv = R2, *xr = R3;
  bf16* k_ = R4;                              // ws+128
  bf16* v_ = (bf16*)(ws + 160 * MB);
  bf16* r_ = (bf16*)(ws + 192 * MB);
  bf16* rwkv = R1;                            // xk dead after kvr

  // ChannelMix
  bf16* xk2 = R1, *xr2 = R2, *sig = R3, *kf = R4;
  bf16* Wcr_b = (bf16*)(ws + 224 * MB);       // free region; read by sig-GEMM, then
                                              // kf (128..256) clobbers it afterwards
  bf16* Wck_b = R0;                           // R0 fully dead after Wo-GEMM
  bf16* Wcv_b = R2;                           // xr2 dead after sig-GEMM

  // TimeMix weight homes in R0
  bf16* Wk_b = R0;
  bf16* Wv_b = R0 + (size_t)D_ * C_;
  bf16* Wr_b = R0 + (size_t)2 * D_ * C_;
  bf16* Wo_b = R0 + (size_t)3 * D_ * C_;

  // WKV state (6 MB) in R0 head (Wk/Wv/Wr dead after kvr; Wo_b at +24 MiB safe)
  float* sA = (float*)R0;
  float* sB = sA + (size_t)B_ * NCH * D_;
  float* sP = sB + (size_t)B_ * NCH * D_;

  const int gN2k = (BT_ / 256) * (D_ / 256);   // 256 blocks

  // --- TimeMix ---
  mixcvt1_kernel<<<BT_ + 4096, 256, 0, stream>>>(x, ln1w, ln1b, tmk, tmv, tmr,
      xk, xv, xr, Wk, Wv, Wr, Wo, Wk_b, Wv_b, Wr_b, Wo_b);
  gemm_kvr_cvt<<<1280, 512, 0, stream>>>(xk, xv, xr, Wk_b, Wv_b, Wr_b, k_, v_, r_,
      Wcr, Wcr_b);
  wkv_pass1<<<B_ * NCH * D_ / 256, 256, 0, stream>>>(k_, v_, td, sA, sB, sP);
  wkv_pass2<<<B_ * D_ / 256, 256, 0, stream>>>(td, sA, sB, sP);
  wkv_pass3<<<B_ * NCH * D_ / 256, 256, 0, stream>>>(k_, v_, r_, td, tf, sA, sB, sP, rwkv);
  gemm256<2><<<gN2k, 512, 0, stream>>>(rwkv, Wo_b, C_, D_, out, nullptr, x, nullptr);

  // --- ChannelMix ---
  mixcvt2_kernel<<<BT_ + 2048, 256, 0, stream>>>(out, ln2w, ln2b, cmk, cmr,
      xk2, xr2, Wck, Wck_b);
  gemm256<3><<<gN2k, 512, 0, stream>>>(xr2, Wcr_b, C_, C_, nullptr, sig, nullptr, nullptr);
  gemm_kf_cvt<<<1536, 512, 0, stream>>>(xk2, Wck_b, kf, Wcv, Wcv_b);
  gemm256<4><<<gN2k, 512, 0, stream>>>(kf, Wcv_b, C_, F_, out, nullptr, out, sig);
}

// Round 17
// 922.555 us; speedup vs baseline: 1.0033x; 1.0033x over previous
//
#include <hip/hip_runtime.h>
#include <hip/hip_bf16.h>

#define B_ 4
#define T_ 2048
#define C_ 2048
#define D_ 2048
#define F_ 8192
#define BT_ (B_*T_)
#define NCH 64
#define LCH 32

using bf16 = __hip_bfloat16;
typedef __attribute__((ext_vector_type(8))) short bf16x8;
typedef __attribute__((ext_vector_type(4))) float f32x4;

template<bool V> struct BC { static constexpr bool value = V; };

struct bf4 { bf16 a, b, c, d; };

__device__ __forceinline__ bf4 to_bf4(float x, float y, float z, float w) {
  bf4 r;
  r.a = __float2bfloat16(x); r.b = __float2bfloat16(y);
  r.c = __float2bfloat16(z); r.d = __float2bfloat16(w);
  return r;
}

__device__ __forceinline__ void cvt_body(const float* __restrict__ in,
                                         bf16* __restrict__ out,
                                         int i, int stride, int n4) {
  for (; i < n4; i += stride) {
    float4 v = ((const float4*)in)[i];
    ((bf4*)out)[i] = to_bf4(v.x, v.y, v.z, v.w);
  }
}

// ---------------- block-wide reduce of 4 values (256 threads) ----------------
__device__ __forceinline__ void block_reduce4(float v[4], float out[4]) {
  #pragma unroll
  for (int i = 0; i < 4; ++i)
    #pragma unroll
    for (int off = 1; off < 64; off <<= 1)
      v[i] += __shfl_xor(v[i], off);
  __shared__ float red[4][4];
  int wave = threadIdx.x >> 6, lane = threadIdx.x & 63;
  if (lane == 0) {
    red[wave][0] = v[0]; red[wave][1] = v[1];
    red[wave][2] = v[2]; red[wave][3] = v[3];
  }
  __syncthreads();
  #pragma unroll
  for (int i = 0; i < 4; ++i)
    out[i] = red[0][i] + red[1][i] + red[2][i] + red[3][i];
}

// ========== merged: LN+mix (TimeMix) for blocks [0,BT_), cvt4 for the rest ==========
__global__ __launch_bounds__(256) void mixcvt1_kernel(
    const float* __restrict__ x, const float* __restrict__ w, const float* __restrict__ b,
    const float* __restrict__ tmk, const float* __restrict__ tmv, const float* __restrict__ tmr,
    bf16* __restrict__ xk, bf16* __restrict__ xv, bf16* __restrict__ xr,
    const float* __restrict__ W0, const float* __restrict__ W1,
    const float* __restrict__ W2, const float* __restrict__ W3,
    bf16* __restrict__ o0, bf16* __restrict__ o1,
    bf16* __restrict__ o2, bf16* __restrict__ o3) {
  if (blockIdx.x >= BT_) {
    const int lb4 = blockIdx.x - BT_;
    const int sub = lb4 >> 10;
    const int lb = lb4 & 1023;
    const float* in = (sub == 0) ? W0 : (sub == 1) ? W1 : (sub == 2) ? W2 : W3;
    bf16* o = (sub == 0) ? o0 : (sub == 1) ? o1 : (sub == 2) ? o2 : o3;
    cvt_body(in, o, lb * 256 + threadIdx.x, 1024 * 256, D_ * C_ / 4);
    return;
  }
  const int row = blockIdx.x;
  const int t = row & (T_ - 1);
  const bool hasPrev = (t != 0);
  const int tid = threadIdx.x;
  const float* xc = x + (size_t)row * C_;
  const float* xp = xc - C_;
  float c[8], p[8];
  *(float4*)&c[0] = *(const float4*)(xc + tid * 4);
  *(float4*)&c[4] = *(const float4*)(xc + tid * 4 + 1024);
  if (hasPrev) {
    *(float4*)&p[0] = *(const float4*)(xp + tid * 4);
    *(float4*)&p[4] = *(const float4*)(xp + tid * 4 + 1024);
  } else {
    #pragma unroll
    for (int j = 0; j < 8; ++j) p[j] = 0.f;
  }
  float v[4] = {0.f, 0.f, 0.f, 0.f}, tot[4];
  #pragma unroll
  for (int j = 0; j < 8; ++j) {
    v[0] += c[j]; v[1] += c[j] * c[j];
    v[2] += p[j]; v[3] += p[j] * p[j];
  }
  block_reduce4(v, tot);
  const float muc = tot[0] * (1.f / C_);
  const float rsc = rsqrtf(tot[1] * (1.f / C_) - muc * muc + 1e-5f);
  const float mup = tot[2] * (1.f / C_);
  const float rsp = rsqrtf(tot[3] * (1.f / C_) - mup * mup + 1e-5f);
  float wv[8], bv[8], mk[8], mv[8], mr[8];
  #pragma unroll
  for (int half = 0; half < 2; ++half) {
    int i = tid * 4 + half * 1024;
    *(float4*)&wv[half*4] = *(const float4*)(w + i);
    *(float4*)&bv[half*4] = *(const float4*)(b + i);
    *(float4*)&mk[half*4] = *(const float4*)(tmk + i);
    *(float4*)&mv[half*4] = *(const float4*)(tmv + i);
    *(float4*)&mr[half*4] = *(const float4*)(tmr + i);
  }
  float ok[8], ov[8], orr[8];
  #pragma unroll
  for (int j = 0; j < 8; ++j) {
    float h  = (c[j] - muc) * rsc * wv[j] + bv[j];
    float hh = hasPrev ? ((p[j] - mup) * rsp * wv[j] + bv[j]) : 0.f;
    ok[j]  = hh + mk[j] * (h - hh);
    ov[j]  = hh + mv[j] * (h - hh);
    orr[j] = hh + mr[j] * (h - hh);
  }
  size_t ro = (size_t)row * C_;
  #pragma unroll
  for (int half = 0; half < 2; ++half) {
    int i = tid * 4 + half * 1024;
    *(bf4*)(xk + ro + i) = to_bf4(ok[half*4], ok[half*4+1], ok[half*4+2], ok[half*4+3]);
    *(bf4*)(xv + ro + i) = to_bf4(ov[half*4], ov[half*4+1], ov[half*4+2], ov[half*4+3]);
    *(bf4*)(xr + ro + i) = to_bf4(orr[half*4], orr[half*4+1], orr[half*4+2], orr[half*4+3]);
  }
}

// ========== merged: LN+mix (ChannelMix) for [0,BT_), Wck cvt after ==========
__global__ __launch_bounds__(256) void mixcvt2_kernel(
    const float* __restrict__ x, const float* __restrict__ w, const float* __restrict__ b,
    const float* __restrict__ cmk, const float* __restrict__ cmr,
    bf16* __restrict__ xk2, bf16* __restrict__ xr2,
    const float* __restrict__ Wck, bf16* __restrict__ Wck_b) {
  if (blockIdx.x >= BT_) {
    const int lb = blockIdx.x - BT_;
    cvt_body(Wck, Wck_b, lb * 256 + threadIdx.x, 2048 * 256, F_ * C_ / 4);
    return;
  }
  const int row = blockIdx.x;
  const int t = row & (T_ - 1);
  const bool hasPrev = (t != 0);
  const int tid = threadIdx.x;
  const float* xc = x + (size_t)row * C_;
  const float* xp = xc - C_;
  float c[8], p[8];
  *(float4*)&c[0] = *(const float4*)(xc + tid * 4);
  *(float4*)&c[4] = *(const float4*)(xc + tid * 4 + 1024);
  if (hasPrev) {
    *(float4*)&p[0] = *(const float4*)(xp + tid * 4);
    *(float4*)&p[4] = *(const float4*)(xp + tid * 4 + 1024);
  } else {
    #pragma unroll
    for (int j = 0; j < 8; ++j) p[j] = 0.f;
  }
  float v[4] = {0.f, 0.f, 0.f, 0.f}, tot[4];
  #pragma unroll
  for (int j = 0; j < 8; ++j) {
    v[0] += c[j]; v[1] += c[j] * c[j];
    v[2] += p[j]; v[3] += p[j] * p[j];
  }
  block_reduce4(v, tot);
  const float muc = tot[0] * (1.f / C_);
  const float rsc = rsqrtf(tot[1] * (1.f / C_) - muc * muc + 1e-5f);
  const float mup = tot[2] * (1.f / C_);
  const float rsp = rsqrtf(tot[3] * (1.f / C_) - mup * mup + 1e-5f);
  float wv[8], bv[8], mk[8], mr[8];
  #pragma unroll
  for (int half = 0; half < 2; ++half) {
    int i = tid * 4 + half * 1024;
    *(float4*)&wv[half*4] = *(const float4*)(w + i);
    *(float4*)&bv[half*4] = *(const float4*)(b + i);
    *(float4*)&mk[half*4] = *(const float4*)(cmk + i);
    *(float4*)&mr[half*4] = *(const float4*)(cmr + i);
  }
  float ok[8], orr[8];
  #pragma unroll
  for (int j = 0; j < 8; ++j) {
    float h  = (c[j] - muc) * rsc * wv[j] + bv[j];
    float hh = hasPrev ? ((p[j] - mup) * rsp * wv[j] + bv[j]) : 0.f;
    ok[j]  = hh + mk[j] * (h - hh);
    orr[j] = hh + mr[j] * (h - hh);
  }
  size_t ro = (size_t)row * C_;
  #pragma unroll
  for (int half = 0; half < 2; ++half) {
    int i = tid * 4 + half * 1024;
    *(bf4*)(xk2 + ro + i) = to_bf4(ok[half*4], ok[half*4+1], ok[half*4+2], ok[half*4+3]);
    *(bf4*)(xr2 + ro + i) = to_bf4(orr[half*4], orr[half*4+1], orr[half*4+2], orr[half*4+3]);
  }
}

// ================= chunk-parallel WKV =================
__global__ __launch_bounds__(256) void wkv_pass1(
    const bf16* __restrict__ kp, const bf16* __restrict__ vp,
    const float* __restrict__ td,
    float* __restrict__ sA, float* __restrict__ sB, float* __restrict__ sP) {
  const int g = blockIdx.x * 256 + threadIdx.x;   // b(2) | c(6) | d(11)
  const int d = g & (D_ - 1);
  const int c = (g >> 11) & (NCH - 1);
  const int b = g >> 17;
  const float w = -__expf(td[d]);
  const size_t base = ((size_t)b * T_ + c * LCH) * D_ + d;
  float aa = 0.f, bb = 0.f, pp = -1e38f;
  #pragma unroll 4
  for (int j = 0; j < LCH; ++j) {
    float kt = __bfloat162float(kp[base + (size_t)j * D_]);
    float vt = __bfloat162float(vp[base + (size_t)j * D_]);
    float ww2 = pp + w;
    float p2 = fmaxf(ww2, kt);
    float e1 = __expf(ww2 - p2), e2 = __expf(kt - p2);
    aa = e1 * aa + e2 * vt;
    bb = e1 * bb + e2;
    pp = p2;
  }
  const int sidx = ((b * NCH + c) << 11) + d;
  sA[sidx] = aa; sB[sidx] = bb; sP[sidx] = pp;
}

// serial exclusive prefix over chunks: thread = (b,d), coalesced across d
__global__ __launch_bounds__(256) void wkv_pass2(
    const float* __restrict__ td,
    float* __restrict__ sA, float* __restrict__ sB, float* __restrict__ sP) {
  const int g = blockIdx.x * 256 + threadIdx.x;   // b(2) | d(11)
  const int d = g & (D_ - 1);
  const int b = g >> 11;
  const float wL = -__expf(td[d]) * (float)LCH;
  float aa = 0.f, bb = 0.f, pp = -1e38f;
  for (int c = 0; c < NCH; ++c) {
    const int sidx = ((b * NCH + c) << 11) + d;
    float la = sA[sidx], lb = sB[sidx], lp = sP[sidx];
    sA[sidx] = aa; sB[sidx] = bb; sP[sidx] = pp;   // exclusive prefix
    float ww2 = pp + wL;
    float q = fmaxf(ww2, lp);
    float e1 = __expf(ww2 - q), e2 = __expf(lp - q);
    aa = e1 * aa + e2 * la;
    bb = e1 * bb + e2 * lb;
    pp = q;
  }
}

__global__ __launch_bounds__(256) void wkv_pass3(
    const bf16* __restrict__ kp, const bf16* __restrict__ vp, const bf16* __restrict__ rp,
    const float* __restrict__ td, const float* __restrict__ tfp,
    const float* __restrict__ sA, const float* __restrict__ sB, const float* __restrict__ sP,
    bf16* __restrict__ rwkv) {
  const int g = blockIdx.x * 256 + threadIdx.x;
  const int d = g & (D_ - 1);
  const int c = (g >> 11) & (NCH - 1);
  const int b = g >> 17;
  const float w = -__expf(td[d]);
  const float u = tfp[d];
  const int sidx = ((b * NCH + c) << 11) + d;
  float aa = sA[sidx], bb = sB[sidx], pp = sP[sidx];
  const size_t base = ((size_t)b * T_ + c * LCH) * D_ + d;
  #pragma unroll 4
  for (int j = 0; j < LCH; ++j) {
    float kt = __bfloat162float(kp[base + (size_t)j * D_]);
    float vt = __bfloat162float(vp[base + (size_t)j * D_]);
    float rt = __bfloat162float(rp[base + (size_t)j * D_]);
    float ww = u + kt;
    float p = fmaxf(pp, ww);
    float e1 = __expf(pp - p);
    float e2 = __expf(ww - p);
    float outv = (e1 * aa + e2 * vt) / (e1 * bb + e2);
    float sr = 1.f / (1.f + __expf(-rt));
    rwkv[base + (size_t)j * D_] = __float2bfloat16(sr * outv);
    float ww2 = pp + w;
    float p2 = fmaxf(ww2, kt);
    float e1b = __expf(ww2 - p2);
    float e2b = __expf(kt - p2);
    aa = e1b * aa + e2b * vt;
    bb = e1b * bb + e2b;
    pp = p2;
  }
}

// ================= 256x256 8-phase bf16 MFMA GEMM core (r11 body) =================
template<int EPI>
__device__ __forceinline__ void gemm_core(
    const bf16* __restrict__ A, const bf16* __restrict__ Bt,
    int N, int K, int id, int nwg,
    float* __restrict__ outF, bf16* __restrict__ outB,
    const float* __restrict__ addP, const bf16* __restrict__ sigP,
    char* lds) {
  const int tid = threadIdx.x;
  const int wid = tid >> 6, lane = tid & 63;
  const int wm = wid >> 2, wn = wid & 3;

  const int cpx = nwg >> 3;
  const int sid = (id & 7) * cpx + (id >> 3);
  const int nx = N >> 8;
  const int band = sid / (4 * nx);
  const int rem = sid - band * (4 * nx);
  const int bx = rem >> 2;
  const int by = band * 4 + (rem & 3);
  const int tileM = by * 256, tileN = bx * 256;

  const int NT = K >> 6;

  const int srow_lo = wid * 8 + (lane >> 3);
  const int scel = ((lane & 7) ^ (lane >> 3)) << 3;

  const bf16* pA[2][2];
  const bf16* pB[2][2];
  #pragma unroll
  for (int h = 0; h < 2; ++h)
    #pragma unroll
    for (int j = 0; j < 2; ++j) {
      pA[h][j] = A  + (size_t)(tileM + h * 128 + srow_lo + j * 64) * K + scel;
      pB[h][j] = Bt + (size_t)(tileN + h * 128 + srow_lo + j * 64) * K + scel;
    }
  const int ldsW = wid * 1024;

  auto stA = [&](int par, int h, int eo) {
    #pragma unroll
    for (int j = 0; j < 2; ++j)
      __builtin_amdgcn_global_load_lds(
          (const __attribute__((address_space(1))) void*)(pA[h][j] + eo),
          (__attribute__((address_space(3))) void*)(lds + par * 32768 + h * 16384 + j * 8192 + ldsW),
          16, 0, 0);
  };
  auto stB = [&](int par, int h, int eo) {
    #pragma unroll
    for (int j = 0; j < 2; ++j)
      __builtin_amdgcn_global_load_lds(
          (const __attribute__((address_space(1))) void*)(pB[h][j] + eo),
          (__attribute__((address_space(3))) void*)(lds + 65536 + par * 32768 + h * 16384 + j * 8192 + ldsW),
          16, 0, 0);
  };

  const int lane15 = lane & 15;
  const int kswz0 = ((lane >> 4) * 16) ^ ((lane & 7) << 4);
  const int aBase = (wm * 128 + lane15) * 128;
  const int bBase = (wn * 64 + lane15) * 128;

  f32x4 acc[8][4] = {};

  stB(0, 0, 0); stB(0, 1, 0); stA(0, 0, 0); stA(0, 1, 0); stB(1, 0, 64); stB(1, 1, 64);
  asm volatile("s_waitcnt vmcnt(4)" : : : "memory");
  __builtin_amdgcn_s_barrier();
  __builtin_amdgcn_sched_barrier(0);

  auto tileBody = [&](int par, auto doa, auto dob, int aEo, int bEo) {
    constexpr bool DOA = decltype(doa)::value;
    constexpr bool DOB = decltype(dob)::value;
    const char* Ab = lds + (par << 15);
    const char* Bb = lds + 65536 + (par << 15);
    bf16x8 bfr[4][2];
    #pragma unroll
    for (int q = 0; q < 4; ++q) {
      if (q == 0) {
        #pragma unroll
        for (int n = 0; n < 4; ++n) {
          bfr[n][0] = *(const bf16x8*)(Bb + bBase + n * 2048 + kswz0);
          bfr[n][1] = *(const bf16x8*)(Bb + bBase + n * 2048 + (kswz0 ^ 64));
        }
      }
      bf16x8 am[2][2];
      #pragma unroll
      for (int mm = 0; mm < 2; ++mm) {
        am[mm][0] = *(const bf16x8*)(Ab + aBase + q * 4096 + mm * 2048 + kswz0);
        am[mm][1] = *(const bf16x8*)(Ab + aBase + q * 4096 + mm * 2048 + (kswz0 ^ 64));
      }
      if constexpr (DOA) {
        if (q == 0) stA(par ^ 1, 0, aEo);
        if (q == 1) stA(par ^ 1, 1, aEo);
      }
      if constexpr (DOB) {
        if (q == 2) stB(par, 0, bEo);
        if (q == 3) stB(par, 1, bEo);
      }
      if (q == 0)
        asm volatile("s_waitcnt lgkmcnt(8)" : : : "memory");
      __builtin_amdgcn_sched_barrier(0);
      __builtin_amdgcn_s_barrier();
      __builtin_amdgcn_sched_barrier(0);
      __builtin_amdgcn_s_setprio(1);
      #pragma unroll
      for (int kk = 0; kk < 2; ++kk)
        #pragma unroll
        for (int n = 0; n < 4; ++n) {
          acc[2*q+0][n] = __builtin_amdgcn_mfma_f32_16x16x32_bf16(am[0][kk], bfr[n][kk], acc[2*q+0][n], 0, 0, 0);
          acc[2*q+1][n] = __builtin_amdgcn_mfma_f32_16x16x32_bf16(am[1][kk], bfr[n][kk], acc[2*q+1][n], 0, 0, 0);
        }
      __builtin_amdgcn_s_setprio(0);
      __builtin_amdgcn_sched_barrier(0);
      if (q == 3) {
        if constexpr (DOB)      asm volatile("s_waitcnt vmcnt(4)" : : : "memory");
        else if constexpr (DOA) asm volatile("s_waitcnt vmcnt(0)" : : : "memory");
      }
      __builtin_amdgcn_s_barrier();
      __builtin_amdgcn_sched_barrier(0);
    }
  };

  for (int t = 0; t < NT - 2; t += 2) {
    tileBody(0, BC<true>{}, BC<true>{}, 64, 128);
    tileBody(1, BC<true>{}, BC<true>{}, 128, 192);
    #pragma unroll
    for (int h = 0; h < 2; ++h)
      #pragma unroll
      for (int j = 0; j < 2; ++j) { pA[h][j] += 128; pB[h][j] += 128; }
  }
  tileBody(0, BC<true>{}, BC<false>{}, 64, 0);
  tileBody(1, BC<false>{}, BC<false>{}, 0, 0);

  const int erow0 = tileM + wm * 128 + (lane >> 4) * 4;
  const int ecol0 = tileN + wn * 64 + lane15;
  #pragma unroll
  for (int m = 0; m < 8; ++m) {
    #pragma unroll
    for (int n = 0; n < 4; ++n) {
      #pragma unroll
      for (int r = 0; r < 4; ++r) {
        const int grow = erow0 + m * 16 + r;
        const int gcol = ecol0 + n * 16;
        const size_t idx = (size_t)grow * N + gcol;
        const float val = acc[m][n][r];
        if constexpr (EPI == 0) {
          outB[idx] = __float2bfloat16(val);
        } else if constexpr (EPI == 1) {
          float tt = fmaxf(val, 0.f);
          outB[idx] = __float2bfloat16(tt * tt);
        } else if constexpr (EPI == 2) {
          outF[idx] = addP[idx] + val;
        } else if constexpr (EPI == 3) {
          outB[idx] = __float2bfloat16(1.f / (1.f + __expf(-val)));
        } else {
          outF[idx] = addP[idx] + __bfloat162float(sigP[idx]) * val;
        }
      }
    }
  }
}

template<int EPI>
__global__ __launch_bounds__(512, 2) void gemm256(
    const bf16* __restrict__ A, const bf16* __restrict__ Bt,
    int N, int K,
    float* __restrict__ outF, bf16* __restrict__ outB,
    const float* __restrict__ addP, const bf16* __restrict__ sigP) {
  __shared__ alignas(16) char lds[131072];
  gemm_core<EPI>(A, Bt, N, K, blockIdx.x, gridDim.x, outF, outB, addP, sigP, lds);
}

// merged k/v/r GEMM (blocks 0..767) + trailing Wcr cvt (768..1279)
__global__ __launch_bounds__(512, 2) void gemm_kvr_cvt(
    const bf16* __restrict__ A0, const bf16* __restrict__ A1, const bf16* __restrict__ A2,
    const bf16* __restrict__ B0, const bf16* __restrict__ B1, const bf16* __restrict__ B2,
    bf16* __restrict__ O0, bf16* __restrict__ O1, bf16* __restrict__ O2,
    const float* __restrict__ Wcr, bf16* __restrict__ Wcr_b) {
  __shared__ alignas(16) char lds[131072];
  if (blockIdx.x >= 768) {
    cvt_body(Wcr, Wcr_b, (blockIdx.x - 768) * 512 + threadIdx.x, 512 * 512, C_ * C_ / 4);
    return;
  }
  const int sub = blockIdx.x >> 8;        // 0..2
  const int bid = blockIdx.x & 255;
  const bf16* A  = (sub == 0) ? A0 : (sub == 1) ? A1 : A2;
  const bf16* Bt = (sub == 0) ? B0 : (sub == 1) ? B1 : B2;
  bf16* O        = (sub == 0) ? O0 : (sub == 1) ? O1 : O2;
  gemm_core<0>(A, Bt, D_, C_, bid, 256, nullptr, O, nullptr, nullptr, lds);
}

// fallback path: kf-GEMM (blocks 0..1023) + trailing Wcv cvt (1024..1535)
__global__ __launch_bounds__(512, 2) void gemm_kf_cvt(
    const bf16* __restrict__ A, const bf16* __restrict__ Bt, bf16* __restrict__ kf,
    const float* __restrict__ Wcv, bf16* __restrict__ Wcv_b) {
  __shared__ alignas(16) char lds[131072];
  if (blockIdx.x >= 1024) {
    cvt_body(Wcv, Wcv_b, (blockIdx.x - 1024) * 512 + threadIdx.x, 512 * 512, C_ * F_ / 4);
    return;
  }
  gemm_core<1>(A, Bt, F_, C_, blockIdx.x, 1024, nullptr, kf, nullptr, nullptr, lds);
}

// big-ws path: sig-GEMM (0..255) + kf-GEMM (256..1279) + Wcv cvt (1280..1791)
// alias audit (all post-mixcvt2): sig reads xr2(64..96)+Wcr_b(256..264), writes
// sig(96..128); kf reads xk2(32..64)+Wck_b(0..32), writes kf(128..256); cvt
// writes Wcv_b(264..296). Disjoint.
__global__ __launch_bounds__(512, 2) void gemm_cm(
    const bf16* __restrict__ xr2, const bf16* __restrict__ Wcr_b, bf16* __restrict__ sig,
    const bf16* __restrict__ xk2, const bf16* __restrict__ Wck_b, bf16* __restrict__ kf,
    const float* __restrict__ Wcv, bf16* __restrict__ Wcv_b) {
  __shared__ alignas(16) char lds[131072];
  if (blockIdx.x < 256) {
    gemm_core<3>(xr2, Wcr_b, C_, C_, blockIdx.x, 256, nullptr, sig, nullptr, nullptr, lds);
  } else if (blockIdx.x < 1280) {
    gemm_core<1>(xk2, Wck_b, F_, C_, blockIdx.x - 256, 1024, nullptr, kf, nullptr, nullptr, lds);
  } else {
    cvt_body(Wcv, Wcv_b, (blockIdx.x - 1280) * 512 + threadIdx.x, 512 * 512, C_ * F_ / 4);
  }
}

// ---------------- launch ----------------
extern "C" void kernel_launch(void* const* d_in, const int* in_sizes, int n_in,
                              void* d_out, int out_size, void* d_ws, size_t ws_size,
                              hipStream_t stream) {
  const float* x    = (const float*)d_in[0];
  const float* ln1w = (const float*)d_in[1];
  const float* ln1b = (const float*)d_in[2];
  const float* ln2w = (const float*)d_in[3];
  const float* ln2b = (const float*)d_in[4];
  const float* tmk  = (const float*)d_in[5];
  const float* tmv  = (const float*)d_in[6];
  const float* tmr  = (const float*)d_in[7];
  const float* td   = (const float*)d_in[8];
  const float* tf   = (const float*)d_in[9];
  const float* Wk   = (const float*)d_in[10];
  const float* Wv   = (const float*)d_in[11];
  const float* Wr   = (const float*)d_in[12];
  const float* Wo   = (const float*)d_in[13];
  const float* cmk  = (const float*)d_in[14];
  const float* cmr  = (const float*)d_in[15];
  const float* Wck  = (const float*)d_in[16];
  const float* Wcv  = (const float*)d_in[17];
  const float* Wcr  = (const float*)d_in[18];
  float* out = (float*)d_out;

  char* ws = (char*)d_ws;
  const size_t MB = 1ull << 20;
  bf16* R0 = (bf16*)(ws + 0 * MB);     // TimeMix weights -> wkv state -> Wck_b
  bf16* R1 = (bf16*)(ws + 32 * MB);
  bf16* R2 = (bf16*)(ws + 64 * MB);
  bf16* R3 = (bf16*)(ws + 96 * MB);
  bf16* R4 = (bf16*)(ws + 128 * MB);   // [128,256): k_|v_|r_ then kf (128 MiB)

  const bool bigws = (ws_size >= 296 * MB);

  // TimeMix activations
  bf16* xk = R1, *xv = R2, *xr = R3;
  bf16* k_ = R4;                              // ws+128
  bf16* v_ = (bf16*)(ws + 160 * MB);
  bf16* r_ = (bf16*)(ws + 192 * MB);
  bf16* rwkv = R1;                            // xk dead after kvr

  // ChannelMix
  bf16* xk2 = R1, *xr2 = R2, *sig = R3, *kf = R4;
  // Wcr_b: big-ws -> outside kf span (256..264); else 224..232 (inside kf span,
  // but read by serial sig-GEMM before kf dispatch writes — proven r15/r16)
  bf16* Wcr_b = (bf16*)(ws + (bigws ? 256 : 224) * MB);
  bf16* Wck_b = R0;                           // R0 fully dead after Wo-GEMM
  // Wcv_b: big-ws -> 264..296 (safe vs concurrent xr2 reads); else R2 (xr2 dead
  // after serial sig-GEMM — proven r12-r16)
  bf16* Wcv_b = bigws ? (bf16*)(ws + 264 * MB) : R2;

  // TimeMix weight homes in R0
  bf16* Wk_b = R0;
  bf16* Wv_b = R0 + (size_t)D_ * C_;
  bf16* Wr_b = R0 + (size_t)2 * D_ * C_;
  bf16* Wo_b = R0 + (size_t)3 * D_ * C_;

  // WKV state (6 MB) in R0 head (Wk/Wv/Wr dead after kvr; Wo_b at +24 MiB safe)
  float* sA = (float*)R0;
  float* sB = sA + (size_t)B_ * NCH * D_;
  float* sP = sB + (size_t)B_ * NCH * D_;

  const int gN2k = (BT_ / 256) * (D_ / 256);   // 256 blocks

  // --- TimeMix ---
  mixcvt1_kernel<<<BT_ + 4096, 256, 0, stream>>>(x, ln1w, ln1b, tmk, tmv, tmr,
      xk, xv, xr, Wk, Wv, Wr, Wo, Wk_b, Wv_b, Wr_b, Wo_b);
  gemm_kvr_cvt<<<1280, 512, 0, stream>>>(xk, xv, xr, Wk_b, Wv_b, Wr_b, k_, v_, r_,
      Wcr, Wcr_b);
  wkv_pass1<<<B_ * NCH * D_ / 256, 256, 0, stream>>>(k_, v_, td, sA, sB, sP);
  wkv_pass2<<<B_ * D_ / 256, 256, 0, stream>>>(td, sA, sB, sP);
  wkv_pass3<<<B_ * NCH * D_ / 256, 256, 0, stream>>>(k_, v_, r_, td, tf, sA, sB, sP, rwkv);
  gemm256<2><<<gN2k, 512, 0, stream>>>(rwkv, Wo_b, C_, D_, out, nullptr, x, nullptr);

  // --- ChannelMix ---
  mixcvt2_kernel<<<BT_ + 2048, 256, 0, stream>>>(out, ln2w, ln2b, cmk, cmr,
      xk2, xr2, Wck, Wck_b);
  if (bigws) {
    gemm_cm<<<1792, 512, 0, stream>>>(xr2, Wcr_b, sig, xk2, Wck_b, kf, Wcv, Wcv_b);
  } else {
    gemm256<3><<<gN2k, 512, 0, stream>>>(xr2, Wcr_b, C_, C_, nullptr, sig, nullptr, nullptr);
    gemm_kf_cvt<<<1536, 512, 0, stream>>>(xk2, Wck_b, kf, Wcv, Wcv_b);
  }
  gemm256<4><<<gN2k, 512, 0, stream>>>(kf, Wcv_b, C_, F_, out, nullptr, out, sig);
}